// Round 7
// baseline (398.778 us; speedup 1.0000x reference)
//
#include <hip/hip_runtime.h>

typedef unsigned short u16;
typedef __attribute__((ext_vector_type(8))) __bf16 bf16x8;
typedef __attribute__((ext_vector_type(8))) unsigned short ushort8;
typedef __attribute__((ext_vector_type(4))) float f32x4;

#define MFMA16(a, b, c) __builtin_amdgcn_mfma_f32_16x16x32_bf16((a), (b), (c), 0, 0, 0)

__device__ __forceinline__ u16 f2bf(float f) {
  union { __bf16 h; u16 u; } cv;
  cv.h = (__bf16)f;
  return cv.u;
}

__device__ __forceinline__ void async16(const u16* g, u16* l) {
  __builtin_amdgcn_global_load_lds(
      (const __attribute__((address_space(1))) void*)g,
      (__attribute__((address_space(3))) void*)l, 16, 0, 0);
}

// ---------------- weight transpose fp32 [K][N] -> bf16 [N][K] ----------------
__global__ __launch_bounds__(256)
void transpose_bf16(const float* __restrict__ W, u16* __restrict__ Wt, int K, int N) {
  __shared__ float t[32][33];
  const int n0 = blockIdx.x * 32, k0 = blockIdx.y * 32;
  const int tx = threadIdx.x, ty = threadIdx.y;
  #pragma unroll
  for (int i = 0; i < 32; i += 8)
    t[ty + i][tx] = W[(size_t)(k0 + ty + i) * N + n0 + tx];
  __syncthreads();
  #pragma unroll
  for (int i = 0; i < 32; i += 8)
    Wt[(size_t)(n0 + ty + i) * K + k0 + tx] = f2bf(t[tx][ty + i]);
}

// ---------------- bf16 transpose for V: [B*H][2048][64] -> [B*H][64][2048] ----------------
__global__ __launch_bounds__(256)
void transpose_v(const u16* __restrict__ v, u16* __restrict__ vt) {
  __shared__ u16 t[64][72];
  const int bh = blockIdx.y, t0 = blockIdx.x * 64;
  const int tid = threadIdx.x;
  #pragma unroll
  for (int s = 0; s < 2; ++s) {
    const int idx = tid + s * 256;
    const int row = idx >> 3, ch = idx & 7;
    ushort8 d = *(const ushort8*)(v + ((size_t)bh * 2048 + t0 + row) * 64 + ch * 8);
    #pragma unroll
    for (int e = 0; e < 8; ++e) t[ch * 8 + e][row] = d[e];
  }
  __syncthreads();
  #pragma unroll
  for (int s = 0; s < 2; ++s) {
    const int idx = tid + s * 256;
    const int drow = idx >> 3, ch = idx & 7;
    ushort8 o = *(const ushort8*)(&t[drow][ch * 8]);
    *(ushort8*)(vt + ((size_t)bh * 64 + drow) * 2048 + t0 + ch * 8) = o;
  }
}

// ---------------- layernorm fp32 [4096][1024] -> bf16 ----------------
__global__ __launch_bounds__(256)
void ln_bf16(const float* __restrict__ X, const float* __restrict__ w,
             const float* __restrict__ bia, u16* __restrict__ out) {
  const int row = blockIdx.x, tid = threadIdx.x;
  const float4 v = ((const float4*)(X + (size_t)row * 1024))[tid];
  float s = v.x + v.y + v.z + v.w;
  float s2 = v.x * v.x + v.y * v.y + v.z * v.z + v.w * v.w;
  #pragma unroll
  for (int o = 32; o > 0; o >>= 1) { s += __shfl_down(s, o); s2 += __shfl_down(s2, o); }
  __shared__ float red[8];
  const int wv = tid >> 6, lane = tid & 63;
  if (lane == 0) { red[wv] = s; red[4 + wv] = s2; }
  __syncthreads();
  s = red[0] + red[1] + red[2] + red[3];
  s2 = red[4] + red[5] + red[6] + red[7];
  const float mean = s * (1.f / 1024.f);
  const float var = s2 * (1.f / 1024.f) - mean * mean;
  const float rstd = rsqrtf(var + 1e-5f);
  const float4 wv4 = ((const float4*)w)[tid];
  const float4 bv4 = ((const float4*)bia)[tid];
  ushort4 o;
  o.x = f2bf((v.x - mean) * rstd * wv4.x + bv4.x);
  o.y = f2bf((v.y - mean) * rstd * wv4.y + bv4.y);
  o.z = f2bf((v.z - mean) * rstd * wv4.z + bv4.z);
  o.w = f2bf((v.w - mean) * rstd * wv4.w + bv4.w);
  ((ushort4*)(out + (size_t)row * 1024))[tid] = o;
}

// ---------------- GEMM: C[M,N] = A[M,K] * Bt[N,K]^T ----------------
// BK=64, 128B LDS rows, XOR-8 chunk swizzle.
// MODE 0: qkv scatter (+bias) -> qo/ko/vo [B,H,T,d] bf16
// MODE 2: outB = gelu(acc + bias) (bf16)
// MODE 4: outF[z*M*N + ...] = acc (fp32 partial, split-K)
template <int MODE>
__global__ __launch_bounds__(256)
void gemm_bt(const u16* __restrict__ A, const u16* __restrict__ Bt,
             const float* __restrict__ bias, const float* __restrict__ resid,
             float* __restrict__ outF, u16* __restrict__ outB,
             u16* __restrict__ qo, u16* __restrict__ ko, u16* __restrict__ vo,
             int M, int N, int K, int kSlice) {
  __shared__ u16 As[128 * 64];
  __shared__ u16 Bs[128 * 64];
  const int tid = threadIdx.x;
  const int lane = tid & 63, wv = tid >> 6;
  const int l16 = lane & 15, quad = lane >> 4;
  const int wr = wv >> 1, wc = wv & 1;
  const int m0 = blockIdx.y * 128, n0 = blockIdx.x * 128;
  const int kBegin = blockIdx.z * kSlice, kEnd = kBegin + kSlice;
  const int srow = lane >> 3;
  const int sch = (lane & 7) ^ srow;

  f32x4 acc[4][4];
  const f32x4 fz = {0.f, 0.f, 0.f, 0.f};
  #pragma unroll
  for (int i = 0; i < 4; ++i)
    #pragma unroll
    for (int j = 0; j < 4; ++j) acc[i][j] = fz;

  for (int k0 = kBegin; k0 < kEnd; k0 += 64) {
    __syncthreads();
    #pragma unroll
    for (int s = 0; s < 4; ++s) {
      const int R = wv * 32 + s * 8;
      async16(A + (size_t)(m0 + R + srow) * K + k0 + sch * 8, As + R * 64);
      async16(Bt + (size_t)(n0 + R + srow) * K + k0 + sch * 8, Bs + R * 64);
    }
    __builtin_amdgcn_s_waitcnt(0xF70);  // vmcnt(0)
    __syncthreads();
    #pragma unroll
    for (int h = 0; h < 2; ++h) {
      bf16x8 af[4], bfr[4];
      #pragma unroll
      for (int i = 0; i < 4; ++i) {
        const int row = wr * 64 + i * 16 + l16;
        af[i] = *(const bf16x8*)(As + row * 64 + (((h * 4 + quad) ^ (l16 & 7)) * 8));
      }
      #pragma unroll
      for (int j = 0; j < 4; ++j) {
        const int row = wc * 64 + j * 16 + l16;
        bfr[j] = *(const bf16x8*)(Bs + row * 64 + (((h * 4 + quad) ^ (l16 & 7)) * 8));
      }
      #pragma unroll
      for (int i = 0; i < 4; ++i)
        #pragma unroll
        for (int j = 0; j < 4; ++j)
          acc[i][j] = MFMA16(af[i], bfr[j], acc[i][j]);
    }
  }

  #pragma unroll
  for (int i = 0; i < 4; ++i) {
    #pragma unroll
    for (int j = 0; j < 4; ++j) {
      const int col = n0 + wc * 64 + j * 16 + l16;
      const float bc = bias[col];
      #pragma unroll
      for (int r = 0; r < 4; ++r) {
        const int row = m0 + wr * 64 + i * 16 + quad * 4 + r;
        float v = acc[i][j][r];
        if (MODE != 4) v += bc;
        if (MODE == 0) {
          const int which = col >> 10, cc = col & 1023, hh = cc >> 6, dd = cc & 63;
          const int bb = row >> 11, t = row & 2047;
          const u16 bv = f2bf(v);
          const size_t o = ((size_t)(bb * 16 + hh) * 2048 + t) * 64 + dd;
          if (which == 0)
            qo[o] = bv;
          else if (which == 1)
            ko[o] = bv;
          else
            vo[o] = bv;
        } else if (MODE == 2) {
          const float x3 = v * v * v;
          const float u = 0.7978845608028654f * (v + 0.044715f * x3);
          const float e = __expf(2.f * u);
          const float th = 1.f - 2.f / (e + 1.f);
          outB[(size_t)row * N + col] = f2bf(0.5f * v * (1.f + th));
        } else {
          outF[(size_t)blockIdx.z * M * N + (size_t)row * N + col] = v;
        }
      }
    }
  }
}

// ---------------- split-K reduce: out = resid + bias + P0 + P1 ----------------
__global__ __launch_bounds__(256)
void reduce2(const float* __restrict__ P, const float* __restrict__ resid,
             const float* __restrict__ bias, float* __restrict__ out, int MN, int N) {
  const int idx4 = blockIdx.x * 256 + threadIdx.x;
  const size_t s = (size_t)MN >> 2;
  const float4 a = ((const float4*)P)[idx4];
  const float4 b = ((const float4*)P)[idx4 + s];
  const float4 r = ((const float4*)resid)[idx4];
  const float4 bb = ((const float4*)bias)[idx4 & (N / 4 - 1)];
  float4 o;
  o.x = r.x + a.x + b.x + bb.x;
  o.y = r.y + a.y + b.y + bb.y;
  o.z = r.z + a.z + b.z + bb.z;
  o.w = r.w + a.w + b.w + bb.w;
  ((float4*)out)[idx4] = o;
}

// ---------------- flash attention (causal), 64-row blocks, LPT order ----------------
// block idx: qt = 15 - (idx>>6) (longest first), then (bh, half-band).
// Ps ALIASES Ks (K consumed by QK before P is produced; extra barrier between).
// LDS = 32 KB -> 4-5 blocks/CU. Staging via global_load_lds w16, global-chunk swizzle.
__global__ __launch_bounds__(256, 4)
void attn(const u16* __restrict__ Q, const u16* __restrict__ Kg,
          const u16* __restrict__ Vt, u16* __restrict__ ctx) {
  __shared__ u16 Ks[128 * 64];   // [key][64], slot s <- global chunk s^(key&7); then Ps[64][128]
  __shared__ u16 Vs[64 * 128];   // [d][128],  slot s <- global chunk s^(d&15)
  u16* const Ps = Ks;            // alias: [local q][128], chunk swizzle by q&15
  const int idx = blockIdx.x;
  const int qt = 15 - (idx >> 6);
  const int rest = idx & 63;
  const int bh = rest >> 1, half = rest & 1;
  const int b = bh >> 4, h = bh & 15;
  const int tid = threadIdx.x;
  const int lane = tid & 63, wv = tid >> 6;
  const int l16 = lane & 15, quad = lane >> 4;
  const int rb = half * 64 + wv * 16;      // this wave's 16-row band within the q-tile
  const float S2 = 0.18033688011112042f;   // 0.125 * log2(e)
  const u16* Qb = Q + (size_t)bh * 2048 * 64;
  const u16* Kb = Kg + (size_t)bh * 2048 * 64;
  const u16* Vb = Vt + (size_t)bh * 64 * 2048;

  const int kRow = lane >> 3;
  const int kCh = (lane & 7) ^ (kRow & 7);
  const int vRow = lane >> 4;

  bf16x8 qf[2];
  #pragma unroll
  for (int c = 0; c < 2; ++c)
    qf[c] = *(const bf16x8*)(Qb + (size_t)(qt * 128 + rb + l16) * 64 + c * 32 + quad * 8);

  f32x4 octx[4];
  const f32x4 fz = {0.f, 0.f, 0.f, 0.f};
  #pragma unroll
  for (int jd = 0; jd < 4; ++jd) octx[jd] = fz;
  float mi[4], li[4];
  #pragma unroll
  for (int r = 0; r < 4; ++r) { mi[r] = -1e30f; li[r] = 0.f; }

  for (int kt = 0; kt <= qt; ++kt) {
    __syncthreads();  // prev iter's Ps/Vs reads done before restaging
    #pragma unroll
    for (int s = 0; s < 4; ++s) {
      const int R = wv * 32 + s * 8;
      async16(Kb + (size_t)(kt * 128 + R + kRow) * 64 + kCh * 8, Ks + R * 64);
    }
    #pragma unroll
    for (int s = 0; s < 4; ++s) {
      const int D = wv * 16 + s * 4;
      const int dd = D + vRow;
      const int sch = (lane & 15) ^ (dd & 15);
      async16(Vb + (size_t)dd * 2048 + kt * 128 + sch * 8, Vs + D * 128);
    }
    __builtin_amdgcn_s_waitcnt(0xF70);  // vmcnt(0)
    __syncthreads();

    // S = Q K^T for this wave's 16 q-rows x 128 keys
    f32x4 sa[8];
    #pragma unroll
    for (int j = 0; j < 8; ++j) {
      const int key7 = l16 & 7;
      bf16x8 kf0 = *(const bf16x8*)(Ks + (16 * j + l16) * 64 + ((quad ^ key7) * 8));
      bf16x8 kf1 = *(const bf16x8*)(Ks + (16 * j + l16) * 64 + (((4 + quad) ^ key7) * 8));
      f32x4 tt = MFMA16(qf[0], kf0, fz);
      sa[j] = MFMA16(qf[1], kf1, tt);
    }
    __syncthreads();  // ALL waves done reading Ks before Ps (=Ks) writes

    if (kt == qt) {
      #pragma unroll
      for (int j = 0; j < 8; ++j)
        #pragma unroll
        for (int r = 0; r < 4; ++r) {
          const int rg = rb + quad * 4 + r;
          const int cg = j * 16 + l16;
          if (cg > rg) sa[j][r] = -1e30f;
        }
    }
    #pragma unroll
    for (int r = 0; r < 4; ++r) {
      float mx = -1e30f;
      #pragma unroll
      for (int j = 0; j < 8; ++j) mx = fmaxf(mx, sa[j][r]);
      mx = fmaxf(mx, __shfl_xor(mx, 1));
      mx = fmaxf(mx, __shfl_xor(mx, 2));
      mx = fmaxf(mx, __shfl_xor(mx, 4));
      mx = fmaxf(mx, __shfl_xor(mx, 8));
      mx *= S2;
      const float mn = fmaxf(mi[r], mx);
      const float al = __builtin_amdgcn_exp2f(mi[r] - mn);
      mi[r] = mn;
      const int row = wv * 16 + quad * 4 + r;  // local row 0..63
      const int rl = row & 15;
      float rs = 0.f;
      #pragma unroll
      for (int j = 0; j < 8; ++j) {
        const float p = __builtin_amdgcn_exp2f(sa[j][r] * S2 - mn);
        rs += p;
        const int colc = 2 * j + (l16 >> 3);
        Ps[row * 128 + ((colc ^ rl) * 8) + (l16 & 7)] = f2bf(p);
      }
      rs += __shfl_xor(rs, 1);
      rs += __shfl_xor(rs, 2);
      rs += __shfl_xor(rs, 4);
      rs += __shfl_xor(rs, 8);
      li[r] = li[r] * al + rs;
      #pragma unroll
      for (int jd = 0; jd < 4; ++jd) octx[jd][r] *= al;
    }
    // ctx += P V (lane reads only its wave's Ps rows; same-wave ordering)
    #pragma unroll
    for (int c = 0; c < 4; ++c) {
      const int row = wv * 16 + l16;
      bf16x8 pf = *(const bf16x8*)(Ps + row * 128 + (((c * 4 + quad) ^ l16) * 8));
      #pragma unroll
      for (int jd = 0; jd < 4; ++jd) {
        const int dd = jd * 16 + l16;
        bf16x8 vf = *(const bf16x8*)(Vs + dd * 128 + (((c * 4 + quad) ^ (dd & 15)) * 8));
        octx[jd] = MFMA16(pf, vf, octx[jd]);
      }
    }
  }
  // epilogue: /l, write [B][T][H*d] bf16
  #pragma unroll
  for (int jd = 0; jd < 4; ++jd)
    #pragma unroll
    for (int r = 0; r < 4; ++r) {
      const int rowg = qt * 128 + rb + quad * 4 + r;
      const int col = h * 64 + jd * 16 + l16;
      ctx[((size_t)b * 2048 + rowg) * 1024 + col] = f2bf(octx[jd][r] / li[r]);
    }
}

// ---------------- launch ----------------
extern "C" void kernel_launch(void* const* d_in, const int* in_sizes, int n_in,
                              void* d_out, int out_size, void* d_ws, size_t ws_size,
                              hipStream_t stream) {
  (void)in_sizes; (void)n_in; (void)out_size; (void)ws_size;
  const float* x      = (const float*)d_in[0];
  const float* ln1_w  = (const float*)d_in[1];
  const float* ln1_b  = (const float*)d_in[2];
  const float* w_qkv  = (const float*)d_in[3];
  const float* b_qkv  = (const float*)d_in[4];
  const float* w_attn = (const float*)d_in[5];
  const float* b_attn = (const float*)d_in[6];
  const float* ln2_w  = (const float*)d_in[7];
  const float* ln2_b  = (const float*)d_in[8];
  const float* w_fc   = (const float*)d_in[9];
  const float* b_fc   = (const float*)d_in[10];
  const float* w_proj = (const float*)d_in[11];
  const float* b_proj = (const float*)d_in[12];
  float* out = (float*)d_out;

  char* ws = (char*)d_ws;
  size_t off = 0;
  auto alloc = [&](size_t n) {
    char* p = ws + off;
    off += (n + 255) & ~(size_t)255;
    return p;
  };
  u16* h1     = (u16*)alloc(4096ull * 1024 * 2);
  u16* wqkvT  = (u16*)alloc(3072ull * 1024 * 2);
  u16* wattnT = (u16*)alloc(1024ull * 1024 * 2);
  u16* wfcT   = (u16*)alloc(4096ull * 1024 * 2);
  u16* wprojT = (u16*)alloc(1024ull * 4096 * 2);
  u16* q      = (u16*)alloc(4096ull * 1024 * 2);
  u16* k      = (u16*)alloc(4096ull * 1024 * 2);
  u16* vT     = (u16*)alloc(4096ull * 1024 * 2);
  u16* ctxb   = (u16*)alloc(4096ull * 1024 * 2);
  float* out1 = (float*)alloc(4096ull * 1024 * 4);
  u16* h2     = (u16*)alloc(4096ull * 1024 * 2);
  u16* fco    = (u16*)alloc(4096ull * 4096 * 2);

  u16* vtmp = ctxb;             // dead until attn; raw V [B,H,T,d]
  float* apP = (float*)fco;     // fco dead until FC: attn-proj split-K partials
  float* projP = (float*)q;     // q..ctxb dead after attn-proj: proj partials

  const dim3 tb(32, 8);
  transpose_bf16<<<dim3(3072 / 32, 1024 / 32), tb, 0, stream>>>(w_qkv, wqkvT, 1024, 3072);
  transpose_bf16<<<dim3(1024 / 32, 1024 / 32), tb, 0, stream>>>(w_attn, wattnT, 1024, 1024);
  transpose_bf16<<<dim3(4096 / 32, 1024 / 32), tb, 0, stream>>>(w_fc, wfcT, 1024, 4096);
  transpose_bf16<<<dim3(1024 / 32, 4096 / 32), tb, 0, stream>>>(w_proj, wprojT, 4096, 1024);

  ln_bf16<<<4096, 256, 0, stream>>>(x, ln1_w, ln1_b, h1);

  gemm_bt<0><<<dim3(24, 32, 1), 256, 0, stream>>>(h1, wqkvT, b_qkv, nullptr, nullptr,
                                                  nullptr, q, k, vtmp, 4096, 3072, 1024, 1024);

  transpose_v<<<dim3(32, 32), 256, 0, stream>>>(vtmp, vT);

  attn<<<1024, 256, 0, stream>>>(q, k, vT, ctxb);

  // attn-proj: split-K=2 partials into fco, fused reduce + bias + residual(x) -> out1
  gemm_bt<4><<<dim3(8, 32, 2), 256, 0, stream>>>(ctxb, wattnT, b_attn, nullptr, apP, nullptr,
                                                 nullptr, nullptr, nullptr, 4096, 1024, 1024, 512);
  reduce2<<<4096, 256, 0, stream>>>(apP, x, b_attn, out1, 4096 * 1024, 1024);

  ln_bf16<<<4096, 256, 0, stream>>>(out1, ln2_w, ln2_b, h2);

  gemm_bt<2><<<dim3(32, 32, 1), 256, 0, stream>>>(h2, wfcT, b_fc, nullptr, nullptr, fco,
                                                  nullptr, nullptr, nullptr, 4096, 4096, 1024, 1024);

  gemm_bt<4><<<dim3(8, 32, 2), 256, 0, stream>>>(fco, wprojT, b_proj, nullptr, projP, nullptr,
                                                 nullptr, nullptr, nullptr, 4096, 1024, 4096, 2048);

  reduce2<<<4096, 256, 0, stream>>>(projP, out1, b_proj, out, 4096 * 1024, 1024);
}

// Round 8
// 373.410 us; speedup vs baseline: 1.0679x; 1.0679x over previous
//
#include <hip/hip_runtime.h>

typedef unsigned short u16;
typedef __attribute__((ext_vector_type(8))) __bf16 bf16x8;
typedef __attribute__((ext_vector_type(8))) unsigned short ushort8;
typedef __attribute__((ext_vector_type(4))) float f32x4;

#define MFMA16(a, b, c) __builtin_amdgcn_mfma_f32_16x16x32_bf16((a), (b), (c), 0, 0, 0)

__device__ __forceinline__ u16 f2bf(float f) {
  union { __bf16 h; u16 u; } cv;
  cv.h = (__bf16)f;
  return cv.u;
}

__device__ __forceinline__ float bf2f(u16 u) {
  union { float f; unsigned v; } cv;
  cv.v = ((unsigned)u) << 16;
  return cv.f;
}

__device__ __forceinline__ void async16(const u16* g, u16* l) {
  __builtin_amdgcn_global_load_lds(
      (const __attribute__((address_space(1))) void*)g,
      (__attribute__((address_space(3))) void*)l, 16, 0, 0);
}

// ---------------- weight transpose fp32 [K][N] -> bf16 [N][K] ----------------
__global__ __launch_bounds__(256)
void transpose_bf16(const float* __restrict__ W, u16* __restrict__ Wt, int K, int N) {
  __shared__ float t[32][33];
  const int n0 = blockIdx.x * 32, k0 = blockIdx.y * 32;
  const int tx = threadIdx.x, ty = threadIdx.y;
  #pragma unroll
  for (int i = 0; i < 32; i += 8)
    t[ty + i][tx] = W[(size_t)(k0 + ty + i) * N + n0 + tx];
  __syncthreads();
  #pragma unroll
  for (int i = 0; i < 32; i += 8)
    Wt[(size_t)(n0 + ty + i) * K + k0 + tx] = f2bf(t[tx][ty + i]);
}

// ---------------- bf16 transpose for V: [B*H][2048][64] -> [B*H][64][2048] ----------------
__global__ __launch_bounds__(256)
void transpose_v(const u16* __restrict__ v, u16* __restrict__ vt) {
  __shared__ u16 t[64][72];
  const int bh = blockIdx.y, t0 = blockIdx.x * 64;
  const int tid = threadIdx.x;
  #pragma unroll
  for (int s = 0; s < 2; ++s) {
    const int idx = tid + s * 256;
    const int row = idx >> 3, ch = idx & 7;
    ushort8 d = *(const ushort8*)(v + ((size_t)bh * 2048 + t0 + row) * 64 + ch * 8);
    #pragma unroll
    for (int e = 0; e < 8; ++e) t[ch * 8 + e][row] = d[e];
  }
  __syncthreads();
  #pragma unroll
  for (int s = 0; s < 2; ++s) {
    const int idx = tid + s * 256;
    const int drow = idx >> 3, ch = idx & 7;
    ushort8 o = *(const ushort8*)(&t[drow][ch * 8]);
    *(ushort8*)(vt + ((size_t)bh * 64 + drow) * 2048 + t0 + ch * 8) = o;
  }
}

// ---------------- layernorm fp32 [4096][1024] -> bf16 ----------------
__global__ __launch_bounds__(256)
void ln_bf16(const float* __restrict__ X, const float* __restrict__ w,
             const float* __restrict__ bia, u16* __restrict__ out) {
  const int row = blockIdx.x, tid = threadIdx.x;
  const float4 v = ((const float4*)(X + (size_t)row * 1024))[tid];
  float s = v.x + v.y + v.z + v.w;
  float s2 = v.x * v.x + v.y * v.y + v.z * v.z + v.w * v.w;
  #pragma unroll
  for (int o = 32; o > 0; o >>= 1) { s += __shfl_down(s, o); s2 += __shfl_down(s2, o); }
  __shared__ float red[8];
  const int wv = tid >> 6, lane = tid & 63;
  if (lane == 0) { red[wv] = s; red[4 + wv] = s2; }
  __syncthreads();
  s = red[0] + red[1] + red[2] + red[3];
  s2 = red[4] + red[5] + red[6] + red[7];
  const float mean = s * (1.f / 1024.f);
  const float var = s2 * (1.f / 1024.f) - mean * mean;
  const float rstd = rsqrtf(var + 1e-5f);
  const float4 wv4 = ((const float4*)w)[tid];
  const float4 bv4 = ((const float4*)bia)[tid];
  ushort4 o;
  o.x = f2bf((v.x - mean) * rstd * wv4.x + bv4.x);
  o.y = f2bf((v.y - mean) * rstd * wv4.y + bv4.y);
  o.z = f2bf((v.z - mean) * rstd * wv4.z + bv4.z);
  o.w = f2bf((v.w - mean) * rstd * wv4.w + bv4.w);
  ((ushort4*)(out + (size_t)row * 1024))[tid] = o;
}

// ---------------- GEMM: C[M,N] = A[M,K] * Bt[N,K]^T ----------------
// BK=64, 128B LDS rows, XOR-8 chunk swizzle.
// MODE 0: qkv scatter (+bias) -> qo/ko/vo [B,H,T,d] bf16
// MODE 2: outB = gelu(acc + bias) (bf16)
// MODE 4: outF[z*M*N + ...] = acc (fp32 partial, split-K)
// MODE 5: outB[z*M*N + ...] = acc (bf16 partial, split-K)
template <int MODE>
__global__ __launch_bounds__(256)
void gemm_bt(const u16* __restrict__ A, const u16* __restrict__ Bt,
             const float* __restrict__ bias, const float* __restrict__ resid,
             float* __restrict__ outF, u16* __restrict__ outB,
             u16* __restrict__ qo, u16* __restrict__ ko, u16* __restrict__ vo,
             int M, int N, int K, int kSlice) {
  __shared__ u16 As[128 * 64];
  __shared__ u16 Bs[128 * 64];
  const int tid = threadIdx.x;
  const int lane = tid & 63, wv = tid >> 6;
  const int l16 = lane & 15, quad = lane >> 4;
  const int wr = wv >> 1, wc = wv & 1;
  const int m0 = blockIdx.y * 128, n0 = blockIdx.x * 128;
  const int kBegin = blockIdx.z * kSlice, kEnd = kBegin + kSlice;
  const int srow = lane >> 3;
  const int sch = (lane & 7) ^ srow;

  f32x4 acc[4][4];
  const f32x4 fz = {0.f, 0.f, 0.f, 0.f};
  #pragma unroll
  for (int i = 0; i < 4; ++i)
    #pragma unroll
    for (int j = 0; j < 4; ++j) acc[i][j] = fz;

  for (int k0 = kBegin; k0 < kEnd; k0 += 64) {
    __syncthreads();
    #pragma unroll
    for (int s = 0; s < 4; ++s) {
      const int R = wv * 32 + s * 8;
      async16(A + (size_t)(m0 + R + srow) * K + k0 + sch * 8, As + R * 64);
      async16(Bt + (size_t)(n0 + R + srow) * K + k0 + sch * 8, Bs + R * 64);
    }
    __builtin_amdgcn_s_waitcnt(0xF70);  // vmcnt(0)
    __syncthreads();
    #pragma unroll
    for (int h = 0; h < 2; ++h) {
      bf16x8 af[4], bfr[4];
      #pragma unroll
      for (int i = 0; i < 4; ++i) {
        const int row = wr * 64 + i * 16 + l16;
        af[i] = *(const bf16x8*)(As + row * 64 + (((h * 4 + quad) ^ (l16 & 7)) * 8));
      }
      #pragma unroll
      for (int j = 0; j < 4; ++j) {
        const int row = wc * 64 + j * 16 + l16;
        bfr[j] = *(const bf16x8*)(Bs + row * 64 + (((h * 4 + quad) ^ (l16 & 7)) * 8));
      }
      #pragma unroll
      for (int i = 0; i < 4; ++i)
        #pragma unroll
        for (int j = 0; j < 4; ++j)
          acc[i][j] = MFMA16(af[i], bfr[j], acc[i][j]);
    }
  }

  #pragma unroll
  for (int i = 0; i < 4; ++i) {
    #pragma unroll
    for (int j = 0; j < 4; ++j) {
      const int col = n0 + wc * 64 + j * 16 + l16;
      const float bc = bias[col];
      #pragma unroll
      for (int r = 0; r < 4; ++r) {
        const int row = m0 + wr * 64 + i * 16 + quad * 4 + r;
        float v = acc[i][j][r];
        if (MODE != 4 && MODE != 5) v += bc;
        if (MODE == 0) {
          const int which = col >> 10, cc = col & 1023, hh = cc >> 6, dd = cc & 63;
          const int bb = row >> 11, t = row & 2047;
          const u16 bv = f2bf(v);
          const size_t o = ((size_t)(bb * 16 + hh) * 2048 + t) * 64 + dd;
          if (which == 0)
            qo[o] = bv;
          else if (which == 1)
            ko[o] = bv;
          else
            vo[o] = bv;
        } else if (MODE == 2) {
          const float x3 = v * v * v;
          const float u = 0.7978845608028654f * (v + 0.044715f * x3);
          const float e = __expf(2.f * u);
          const float th = 1.f - 2.f / (e + 1.f);
          outB[(size_t)row * N + col] = f2bf(0.5f * v * (1.f + th));
        } else if (MODE == 4) {
          outF[(size_t)blockIdx.z * M * N + (size_t)row * N + col] = v;
        } else {  // MODE 5
          outB[(size_t)blockIdx.z * M * N + (size_t)row * N + col] = f2bf(v);
        }
      }
    }
  }
}

// ---- fused: out1 = x + P0 + P1 + bias ; h2 = LN(out1)*w+b (one pass) ----
__global__ __launch_bounds__(256)
void reduce2_ln(const float* __restrict__ P, const float* __restrict__ x,
                const float* __restrict__ bias, const float* __restrict__ lnw,
                const float* __restrict__ lnb, float* __restrict__ out1,
                u16* __restrict__ h2) {
  const int row = blockIdx.x, tid = threadIdx.x;
  const size_t base4 = (size_t)row * 256;
  const float4 p0 = ((const float4*)P)[base4 + tid];
  const float4 p1 = ((const float4*)P)[base4 + tid + 4096ull * 256];
  const float4 xv = ((const float4*)x)[base4 + tid];
  const float4 bb = ((const float4*)bias)[tid];
  float4 o;
  o.x = xv.x + p0.x + p1.x + bb.x;
  o.y = xv.y + p0.y + p1.y + bb.y;
  o.z = xv.z + p0.z + p1.z + bb.z;
  o.w = xv.w + p0.w + p1.w + bb.w;
  ((float4*)out1)[base4 + tid] = o;
  float s = o.x + o.y + o.z + o.w;
  float s2 = o.x * o.x + o.y * o.y + o.z * o.z + o.w * o.w;
  #pragma unroll
  for (int of = 32; of > 0; of >>= 1) { s += __shfl_down(s, of); s2 += __shfl_down(s2, of); }
  __shared__ float red[8];
  const int wv = tid >> 6, lane = tid & 63;
  if (lane == 0) { red[wv] = s; red[4 + wv] = s2; }
  __syncthreads();
  s = red[0] + red[1] + red[2] + red[3];
  s2 = red[4] + red[5] + red[6] + red[7];
  const float mean = s * (1.f / 1024.f);
  const float var = s2 * (1.f / 1024.f) - mean * mean;
  const float rstd = rsqrtf(var + 1e-5f);
  const float4 wv4 = ((const float4*)lnw)[tid];
  const float4 bv4 = ((const float4*)lnb)[tid];
  ushort4 ho;
  ho.x = f2bf((o.x - mean) * rstd * wv4.x + bv4.x);
  ho.y = f2bf((o.y - mean) * rstd * wv4.y + bv4.y);
  ho.z = f2bf((o.z - mean) * rstd * wv4.z + bv4.z);
  ho.w = f2bf((o.w - mean) * rstd * wv4.w + bv4.w);
  ((ushort4*)h2)[base4 + tid] = ho;
}

// ---- split-K=4 reduce (bf16 partials): out = resid + bias + sum_z Pz ----
__global__ __launch_bounds__(256)
void reduce4b(const u16* __restrict__ P, const float* __restrict__ resid,
              const float* __restrict__ bias, float* __restrict__ out,
              int MN, int N) {
  const int idx4 = blockIdx.x * 256 + threadIdx.x;
  const float4 r = ((const float4*)resid)[idx4];
  const float4 bb = ((const float4*)bias)[idx4 & (N / 4 - 1)];
  float a[4] = {r.x + bb.x, r.y + bb.y, r.z + bb.z, r.w + bb.w};
  #pragma unroll
  for (int z = 0; z < 4; ++z) {
    const ushort4 p = ((const ushort4*)(P + (size_t)z * MN))[idx4];
    a[0] += bf2f(p.x); a[1] += bf2f(p.y); a[2] += bf2f(p.z); a[3] += bf2f(p.w);
  }
  float4 o; o.x = a[0]; o.y = a[1]; o.z = a[2]; o.w = a[3];
  ((float4*)out)[idx4] = o;
}

// ---------------- flash attention (causal), balanced pairing (R6 = best) ----------------
// block = (b,h, pair p, half): 64 q-rows of BOTH q-tiles p and 15-p.
// Staging via global_load_lds width-16; swizzle applied on the GLOBAL source chunk.
__global__ __launch_bounds__(256)
void attn(const u16* __restrict__ Q, const u16* __restrict__ Kg,
          const u16* __restrict__ Vt, u16* __restrict__ ctx) {
  __shared__ u16 Ks[128 * 64];   // [key][64], slot s <- global chunk s^(key&7)
  __shared__ u16 Vs[64 * 128];   // [d][128],  slot s <- global chunk s^(d&15)
  __shared__ u16 Ps[64 * 128];   // [local q][128], chunk swizzle by q&15
  const int px = blockIdx.x;
  const int pair = px >> 1, half = px & 1;
  const int qt0 = pair, qt1 = 15 - pair;
  const int bh = blockIdx.y;
  const int b = bh >> 4, h = bh & 15;
  const int tid = threadIdx.x;
  const int lane = tid & 63, wv = tid >> 6;
  const int l16 = lane & 15, quad = lane >> 4;
  const int rb = half * 64 + wv * 16;
  const u16* Qb = Q + (size_t)bh * 2048 * 64;
  const u16* Kb = Kg + (size_t)bh * 2048 * 64;
  const u16* Vb = Vt + (size_t)bh * 64 * 2048;

  const int kRow = lane >> 3;
  const int kCh = (lane & 7) ^ (kRow & 7);
  const int vRow = lane >> 4;

  bf16x8 qf[2][2];
  #pragma unroll
  for (int t = 0; t < 2; ++t)
    #pragma unroll
    for (int c = 0; c < 2; ++c)
      qf[t][c] = *(const bf16x8*)(Qb + (size_t)((t ? qt1 : qt0) * 128 + rb + l16) * 64 +
                                  c * 32 + quad * 8);

  f32x4 octx[2][4];
  const f32x4 fz = {0.f, 0.f, 0.f, 0.f};
  #pragma unroll
  for (int t = 0; t < 2; ++t)
    #pragma unroll
    for (int jd = 0; jd < 4; ++jd) octx[t][jd] = fz;
  float mi[2][4], li[2][4];
  #pragma unroll
  for (int t = 0; t < 2; ++t)
    #pragma unroll
    for (int r = 0; r < 4; ++r) { mi[t][r] = -1e30f; li[t][r] = 0.f; }

  for (int kt = 0; kt <= qt1; ++kt) {
    __syncthreads();
    #pragma unroll
    for (int s = 0; s < 4; ++s) {
      const int R = wv * 32 + s * 8;
      async16(Kb + (size_t)(kt * 128 + R + kRow) * 64 + kCh * 8, Ks + R * 64);
    }
    #pragma unroll
    for (int s = 0; s < 4; ++s) {
      const int D = wv * 16 + s * 4;
      const int dd = D + vRow;
      const int sch = (lane & 15) ^ (dd & 15);
      async16(Vb + (size_t)dd * 2048 + kt * 128 + sch * 8, Vs + D * 128);
    }
    __builtin_amdgcn_s_waitcnt(0xF70);  // vmcnt(0)
    __syncthreads();

    #pragma unroll
    for (int t = 0; t < 2; ++t) {
      const int qt = t ? qt1 : qt0;
      if (kt > qt) continue;

      f32x4 sa[8];
      #pragma unroll
      for (int j = 0; j < 8; ++j) {
        const int key7 = l16 & 7;
        bf16x8 kf0 = *(const bf16x8*)(Ks + (16 * j + l16) * 64 + ((quad ^ key7) * 8));
        bf16x8 kf1 = *(const bf16x8*)(Ks + (16 * j + l16) * 64 + (((4 + quad) ^ key7) * 8));
        f32x4 tt = MFMA16(qf[t][0], kf0, fz);
        sa[j] = MFMA16(qf[t][1], kf1, tt);
      }
      if (kt == qt) {
        #pragma unroll
        for (int j = 0; j < 8; ++j)
          #pragma unroll
          for (int r = 0; r < 4; ++r) {
            const int rg = rb + quad * 4 + r;
            const int cg = j * 16 + l16;
            if (cg > rg) sa[j][r] = -1e30f;
          }
      }
      #pragma unroll
      for (int r = 0; r < 4; ++r) {
        float mx = -1e30f;
        #pragma unroll
        for (int j = 0; j < 8; ++j) mx = fmaxf(mx, sa[j][r]);
        mx = fmaxf(mx, __shfl_xor(mx, 1));
        mx = fmaxf(mx, __shfl_xor(mx, 2));
        mx = fmaxf(mx, __shfl_xor(mx, 4));
        mx = fmaxf(mx, __shfl_xor(mx, 8));
        mx *= 0.125f;
        const float mn = fmaxf(mi[t][r], mx);
        const float al = __expf(mi[t][r] - mn);
        mi[t][r] = mn;
        const int row = wv * 16 + quad * 4 + r;
        const int rl = row & 15;
        float rs = 0.f;
        #pragma unroll
        for (int j = 0; j < 8; ++j) {
          const float p = __expf(sa[j][r] * 0.125f - mn);
          rs += p;
          const int colc = 2 * j + (l16 >> 3);
          Ps[row * 128 + ((colc ^ rl) * 8) + (l16 & 7)] = f2bf(p);
        }
        rs += __shfl_xor(rs, 1);
        rs += __shfl_xor(rs, 2);
        rs += __shfl_xor(rs, 4);
        rs += __shfl_xor(rs, 8);
        li[t][r] = li[t][r] * al + rs;
        #pragma unroll
        for (int jd = 0; jd < 4; ++jd) octx[t][jd][r] *= al;
      }
      #pragma unroll
      for (int c = 0; c < 4; ++c) {
        const int row = wv * 16 + l16;
        bf16x8 pf = *(const bf16x8*)(Ps + row * 128 + (((c * 4 + quad) ^ l16) * 8));
        #pragma unroll
        for (int jd = 0; jd < 4; ++jd) {
          const int dd = jd * 16 + l16;
          bf16x8 vf = *(const bf16x8*)(Vs + dd * 128 + (((c * 4 + quad) ^ (dd & 15)) * 8));
          octx[t][jd] = MFMA16(pf, vf, octx[t][jd]);
        }
      }
    }
  }
  #pragma unroll
  for (int t = 0; t < 2; ++t) {
    const int qt = t ? qt1 : qt0;
    #pragma unroll
    for (int jd = 0; jd < 4; ++jd)
      #pragma unroll
      for (int r = 0; r < 4; ++r) {
        const int rowg = qt * 128 + rb + quad * 4 + r;
        const int col = h * 64 + jd * 16 + l16;
        ctx[((size_t)b * 2048 + rowg) * 1024 + col] = f2bf(octx[t][jd][r] / li[t][r]);
      }
  }
}

// ---------------- launch ----------------
extern "C" void kernel_launch(void* const* d_in, const int* in_sizes, int n_in,
                              void* d_out, int out_size, void* d_ws, size_t ws_size,
                              hipStream_t stream) {
  (void)in_sizes; (void)n_in; (void)out_size; (void)ws_size;
  const float* x      = (const float*)d_in[0];
  const float* ln1_w  = (const float*)d_in[1];
  const float* ln1_b  = (const float*)d_in[2];
  const float* w_qkv  = (const float*)d_in[3];
  const float* b_qkv  = (const float*)d_in[4];
  const float* w_attn = (const float*)d_in[5];
  const float* b_attn = (const float*)d_in[6];
  const float* ln2_w  = (const float*)d_in[7];
  const float* ln2_b  = (const float*)d_in[8];
  const float* w_fc   = (const float*)d_in[9];
  const float* b_fc   = (const float*)d_in[10];
  const float* w_proj = (const float*)d_in[11];
  const float* b_proj = (const float*)d_in[12];
  float* out = (float*)d_out;

  char* ws = (char*)d_ws;
  size_t off = 0;
  auto alloc = [&](size_t n) {
    char* p = ws + off;
    off += (n + 255) & ~(size_t)255;
    return p;
  };
  u16* h1     = (u16*)alloc(4096ull * 1024 * 2);
  u16* wqkvT  = (u16*)alloc(3072ull * 1024 * 2);
  u16* wattnT = (u16*)alloc(1024ull * 1024 * 2);
  u16* wfcT   = (u16*)alloc(4096ull * 1024 * 2);
  u16* wprojT = (u16*)alloc(1024ull * 4096 * 2);
  u16* q      = (u16*)alloc(4096ull * 1024 * 2);
  u16* k      = (u16*)alloc(4096ull * 1024 * 2);
  u16* vT     = (u16*)alloc(4096ull * 1024 * 2);
  u16* ctxb   = (u16*)alloc(4096ull * 1024 * 2);
  float* out1 = (float*)alloc(4096ull * 1024 * 4);
  u16* h2     = (u16*)alloc(4096ull * 1024 * 2);
  u16* fco    = (u16*)alloc(4096ull * 4096 * 2);

  u16* vtmp = ctxb;             // dead until attn; raw V [B,H,T,d]
  float* apP = (float*)fco;     // fco dead until FC: attn-proj split-K fp32 partials
  u16* projPb = q;              // q..ctxb (32 MB) dead after attn-proj: 4 bf16 partials

  const dim3 tb(32, 8);
  transpose_bf16<<<dim3(3072 / 32, 1024 / 32), tb, 0, stream>>>(w_qkv, wqkvT, 1024, 3072);
  transpose_bf16<<<dim3(1024 / 32, 1024 / 32), tb, 0, stream>>>(w_attn, wattnT, 1024, 1024);
  transpose_bf16<<<dim3(4096 / 32, 1024 / 32), tb, 0, stream>>>(w_fc, wfcT, 1024, 4096);
  transpose_bf16<<<dim3(1024 / 32, 4096 / 32), tb, 0, stream>>>(w_proj, wprojT, 4096, 1024);

  ln_bf16<<<4096, 256, 0, stream>>>(x, ln1_w, ln1_b, h1);

  gemm_bt<0><<<dim3(24, 32, 1), 256, 0, stream>>>(h1, wqkvT, b_qkv, nullptr, nullptr,
                                                  nullptr, q, k, vtmp, 4096, 3072, 1024, 1024);

  transpose_v<<<dim3(32, 32), 256, 0, stream>>>(vtmp, vT);

  attn<<<dim3(16, 32), 256, 0, stream>>>(q, k, vT, ctxb);

  // attn-proj: split-K=2 fp32 partials into fco, then fused reduce+bias+residual+LN2
  gemm_bt<4><<<dim3(8, 32, 2), 256, 0, stream>>>(ctxb, wattnT, b_attn, nullptr, apP, nullptr,
                                                 nullptr, nullptr, nullptr, 4096, 1024, 1024, 512);
  reduce2_ln<<<4096, 256, 0, stream>>>(apP, x, b_attn, ln2_w, ln2_b, out1, h2);

  gemm_bt<2><<<dim3(32, 32, 1), 256, 0, stream>>>(h2, wfcT, b_fc, nullptr, nullptr, fco,
                                                  nullptr, nullptr, nullptr, 4096, 4096, 1024, 1024);

  // proj: split-K=4 bf16 partials (4 blocks/CU), fused reduce + bias + residual
  gemm_bt<5><<<dim3(8, 32, 4), 256, 0, stream>>>(fco, wprojT, b_proj, nullptr, nullptr, projPb,
                                                 nullptr, nullptr, nullptr, 4096, 1024, 4096, 1024);
  reduce4b<<<4096, 256, 0, stream>>>(projPb, out1, b_proj, out, 4096 * 1024, 1024);
}